// Round 6
// baseline (290.810 us; speedup 1.0000x reference)
//
#include <hip/hip_runtime.h>
#include <cstdint>
#include <cstddef>

// Problem constants (fixed by reference setup_inputs)
#define HW_      65536     // 256*256
#define NB       8         // batch
#define NC       8         // colour dim
#define NF       64        // feature dim
#define NK       8         // K_STEPS
#define NT       256       // threads per block
#define PX       4         // pixels per thread (float4)
#define CHUNK_PX (NT * PX)        // 1024 px per block
#define NCH      (HW_ / CHUNK_PX) // 64 blocks per batch

// log(0.01f), log(0.99f)
#define LN_LO  (-4.6051702f)
#define LN_HI  (-0.010050336f)

// d_out layout (floats):
//   log_m_k : (NK+1)*NB*HW_
//   log_s_k : (NK+1)*NB*HW_
//   colour  : NB*NC*HW_
//   seeds   : NK*NB*NC
#define LMK_SZ ((size_t)(NK + 1) * NB * HW_)
#define COL_SZ ((size_t)NB * NC * HW_)

typedef unsigned long long u64;

// Packed argmax candidate: high 32 bits = float bits of p (p >= 0 so the
// bit pattern is order-preserving), low 32 bits = ~idx so that for equal p
// the SMALLER index wins under max (jnp.argmax first-match tie-break).
__device__ __forceinline__ u64 pack_pi(float v, int idx) {
    return ((u64)__float_as_uint(v) << 32) | (unsigned)(~(unsigned)idx);
}
__device__ __forceinline__ int unpack_idx(u64 p) {
    return (int)(~(unsigned)(p & 0xffffffffull));
}

__device__ __forceinline__ void argmax_cmp(float& bv, int& bi, float ov, int oi) {
    if (ov > bv || (ov == bv && oi < bi)) { bv = ov; bi = oi; }
}

__device__ __forceinline__ void wave_argmax(float& bv, int& bi) {
#pragma unroll
    for (int off = 32; off > 0; off >>= 1) {
        float ov = __shfl_down(bv, off);
        int   oi = __shfl_down(bi, off);
        argmax_cmp(bv, bi, ov, oi);
    }
}

// Block-wide argmax of (bv,bi) followed by one device-scope atomicMax publish.
__device__ __forceinline__ void block_argmax_publish(float bv, int bi, u64* slot,
                                                     float* swv, int* swi,
                                                     int tid, int lane, int wid) {
    wave_argmax(bv, bi);
    if (lane == 0) { swv[wid] = bv; swi[wid] = bi; }
    __syncthreads();
    if (tid == 0) {
        float v = swv[0]; int ii = swi[0];
#pragma unroll
        for (int w = 1; w < NT / 64; ++w) argmax_cmp(v, ii, swv[w], swi[w]);
        atomicMax(slot, pack_pi(v, ii));
    }
}

// ---------------------------------------------------------------------------
// Kernel 1: colour = einsum('bfhw,cf->bchw', features, W) + b
//           + fused step-0 argmax publish (scope == 1 -> p = rand)
// ---------------------------------------------------------------------------
__global__ __launch_bounds__(NT)
void colour_init_kernel(const float* __restrict__ feat, const float* __restrict__ Wm,
                        const float* __restrict__ bias, const float* __restrict__ rand_pix,
                        float* __restrict__ colour, u64* __restrict__ packed) {
    __shared__ float sW[NC * NF];
    __shared__ float sB[NC];
    __shared__ float swv[NT / 64];
    __shared__ int   swi[NT / 64];
    const int tid = threadIdx.x, lane = tid & 63, wid = tid >> 6;
    for (int i = tid; i < NC * NF; i += NT) sW[i] = Wm[i];
    if (tid < NC) sB[tid] = bias[tid];
    __syncthreads();

    const int b   = blockIdx.y;
    const int hw0 = blockIdx.x * CHUNK_PX + tid * PX;
    const float* fb = feat + (size_t)b * NF * HW_ + hw0;

    // rand load issued early (independent of the f-loop)
    float4 r = *reinterpret_cast<const float4*>(rand_pix + (size_t)b * HW_ + hw0);

    float4 acc[NC];
#pragma unroll
    for (int c = 0; c < NC; ++c) acc[c] = make_float4(0.f, 0.f, 0.f, 0.f);

    for (int f = 0; f < NF; ++f) {
        float4 v = *reinterpret_cast<const float4*>(fb + (size_t)f * HW_);
#pragma unroll
        for (int c = 0; c < NC; ++c) {
            float w = sW[c * NF + f];
            acc[c].x = fmaf(v.x, w, acc[c].x);
            acc[c].y = fmaf(v.y, w, acc[c].y);
            acc[c].z = fmaf(v.z, w, acc[c].z);
            acc[c].w = fmaf(v.w, w, acc[c].w);
        }
    }

    float* cb = colour + (size_t)b * NC * HW_ + hw0;
#pragma unroll
    for (int c = 0; c < NC; ++c) {
        float4 o = acc[c];
        float bc = sB[c];
        o.x += bc; o.y += bc; o.z += bc; o.w += bc;
        *reinterpret_cast<float4*>(cb + (size_t)c * HW_) = o;
    }

    // fused init argmax: p = rand (scope == 1)
    float bv = r.x; int bi = hw0;
    argmax_cmp(bv, bi, r.y, hw0 + 1);
    argmax_cmp(bv, bi, r.z, hw0 + 2);
    argmax_cmp(bv, bi, r.w, hw0 + 3);
    block_argmax_publish(bv, bi, &packed[0 * NB + b], swv, swi, tid, lane, wid);
}

// ---------------------------------------------------------------------------
// Kernel 2: one scan step (4 px/thread, 512 blocks).
//  head: 8 threads atomic-load the packed winner -> idx -> gather seed
//  body: dist/alpha/log updates (per-pixel, registers)
//  tail: block argmax of p = rand * exp(log_s_new) -> one atomicMax
// ---------------------------------------------------------------------------
__global__ __launch_bounds__(NT)
void step_kernel(const float* __restrict__ colour, const float* __restrict__ rand_pix,
                 const float* __restrict__ log_sigma_p,
                 float* __restrict__ log_m_k, float* __restrict__ log_s_k,
                 float* __restrict__ seeds, u64* __restrict__ packed, int k) {
    const int b = blockIdx.y, chunk = blockIdx.x, tid = threadIdx.x;
    const int lane = tid & 63, wid = tid >> 6;

    const int    hw0  = chunk * CHUNK_PX + tid * PX;
    const size_t base = (size_t)b * HW_ + hw0;

    __shared__ float sSeed[NC];
    __shared__ float swv[NT / 64];
    __shared__ int   swi[NT / 64];

    // ---- head: dependent chain confined to 8 threads ----
    if (tid < NC) {
        u64 pk = __hip_atomic_load(&packed[k * NB + b], __ATOMIC_RELAXED,
                                   __HIP_MEMORY_SCOPE_AGENT);
        int idx = unpack_idx(pk);
        float sc = colour[((size_t)b * NC + tid) * HW_ + idx];
        sSeed[tid] = sc;
        if (chunk == 0) seeds[((size_t)k * NB + b) * NC + tid] = sc;
    }

    // ---- bulk independent loads (issued while head chain is in flight) ----
    float4 cv[NC];
    const float* cbp = colour + (size_t)b * NC * HW_ + hw0;
#pragma unroll
    for (int c = 0; c < NC; ++c)
        cv[c] = *reinterpret_cast<const float4*>(cbp + (size_t)c * HW_);
    float4 r4 = *reinterpret_cast<const float4*>(rand_pix + base);
    float4 ls4;
    if (k == 0) {
        ls4 = make_float4(0.f, 0.f, 0.f, 0.f);
        *reinterpret_cast<float4*>(log_s_k + base) = ls4;   // log_s_k[0] = 0
    } else {
        ls4 = *reinterpret_cast<const float4*>(log_s_k + (size_t)k * NB * HW_ + base);
    }
    const float inv_sigma = expf(-log_sigma_p[0]);

    __syncthreads();

    // ---- per-pixel update ----
    float ls[PX] = {ls4.x, ls4.y, ls4.z, ls4.w};
    float rp[PX] = {r4.x, r4.y, r4.z, r4.w};
    float lm[PX], ln_[PX];
#pragma unroll
    for (int p = 0; p < PX; ++p) {
        float d = 0.f;
#pragma unroll
        for (int c = 0; c < NC; ++c) {
            float cvp = (p == 0) ? cv[c].x : (p == 1) ? cv[c].y : (p == 2) ? cv[c].z : cv[c].w;
            float diff = cvp - sSeed[c];
            d = fmaf(diff, diff, d);
        }
        float t  = -d * inv_sigma;                    // log(alpha) pre-clamp
        float tc = fminf(fmaxf(t, LN_LO), LN_HI);     // log(clip(alpha))
        float a  = expf(tc);
        lm[p]  = ls[p] + tc;
        ln_[p] = ls[p] + logf(1.0f - a);
    }

    *reinterpret_cast<float4*>(log_m_k + (size_t)k * NB * HW_ + base) =
        make_float4(lm[0], lm[1], lm[2], lm[3]);
    *reinterpret_cast<float4*>(log_s_k + (size_t)(k + 1) * NB * HW_ + base) =
        make_float4(ln_[0], ln_[1], ln_[2], ln_[3]);

    if (k == NK - 1) {
        // log_m_k[K] = last_log_s
        *reinterpret_cast<float4*>(log_m_k + (size_t)NK * NB * HW_ + base) =
            make_float4(ln_[0], ln_[1], ln_[2], ln_[3]);
    } else {
        // ---- tail: publish next step's argmax candidate ----
        float bv = rp[0] * expf(ln_[0]); int bi = hw0;
        argmax_cmp(bv, bi, rp[1] * expf(ln_[1]), hw0 + 1);
        argmax_cmp(bv, bi, rp[2] * expf(ln_[2]), hw0 + 2);
        argmax_cmp(bv, bi, rp[3] * expf(ln_[3]), hw0 + 3);
        block_argmax_publish(bv, bi, &packed[(k + 1) * NB + b], swv, swi, tid, lane, wid);
    }
}

// ---------------------------------------------------------------------------
extern "C" void kernel_launch(void* const* d_in, const int* in_sizes, int n_in,
                              void* d_out, int out_size, void* d_ws, size_t ws_size,
                              hipStream_t stream) {
    const float* feat      = (const float*)d_in[0];  // [8,64,256,256]
    const float* Wm        = (const float*)d_in[1];  // [8,64]
    const float* bias      = (const float*)d_in[2];  // [8]
    const float* log_sigma = (const float*)d_in[3];  // [1]
    const float* rand_pix  = (const float*)d_in[4];  // [8,1,256,256]
    // d_in[5] = steps_to_run (== NK, fixed)

    float* out     = (float*)d_out;
    float* log_m_k = out;              // (NK+1)*NB*HW_
    float* log_s_k = out + LMK_SZ;     // (NK+1)*NB*HW_
    float* colour  = out + 2 * LMK_SZ; // NB*NC*HW_
    float* seeds   = colour + COL_SZ;  // NK*NB*NC

    // workspace: packed argmax slots [NK+1][NB] u64 (slot k = winner for step k)
    u64* packed = (u64*)d_ws;
    hipMemsetAsync(packed, 0, (NK + 1) * NB * sizeof(u64), stream);

    dim3 grid(NCH, NB);
    colour_init_kernel<<<grid, NT, 0, stream>>>(feat, Wm, bias, rand_pix, colour, packed);

    for (int k = 0; k < NK; ++k) {
        step_kernel<<<grid, NT, 0, stream>>>(
            colour, rand_pix, log_sigma,
            log_m_k, log_s_k, seeds, packed, k);
    }
}